// Round 9
// baseline (52.447 us; speedup 1.0000x reference)
//
#include <hip/hip_runtime.h>
#include <hip/hip_bf16.h>

// EnvironmentSpecificDecoder — MI355X bf16-MFMA, round 9.
// R5 skeleton (proven correct) + validated deltas only:
//   - mc path from global Zc fragments + per-wave cp (validated via mu in R6-R8)
//   - Zcb/s_cpart deleted; M1buf keeps its OWN region (no overlay)
//   - epilogue store from lanes 0-15 ONLY (R5's pattern; R6-R8's upper-lane
//     sigma stores correlated perfectly with the sigma-only failures)
// B=32,T=64,d=128,L=64,H=256,H2=128,N_ENVS=8. out = [mu(262144) | sigma(262144)] fp32.

typedef __attribute__((ext_vector_type(8))) short short8;   // 8 x bf16 (4 VGPR)
typedef __attribute__((ext_vector_type(4))) float f32x4;

#define MFMA16(a, b, c) __builtin_amdgcn_mfma_f32_16x16x32_bf16((a), (b), (c), 0, 0, 0)

__device__ __forceinline__ unsigned short f2bf(float f) {   // setup-side only
  union { float f; unsigned u; } v; v.f = f;
  unsigned r = v.u + 0x7fffu + ((v.u >> 16) & 1u);  // RNE
  return (unsigned short)(r >> 16);
}

__device__ __forceinline__ unsigned pkbf(float a, float b) {  // v_cvt_pk_bf16_f32
  __hip_bfloat162 t = __float22bfloat162_rn(float2{a, b});
  unsigned u; __builtin_memcpy(&u, &t, 4); return u;
}

union S8 { short8 s; unsigned u[4]; };

__device__ __forceinline__ void gload16(const void* gsrc, void* ldsdst) {
  __builtin_amdgcn_global_load_lds(
      (const __attribute__((address_space(1))) unsigned int*)gsrc,
      (__attribute__((address_space(3))) unsigned int*)ldsdst, 16, 0, 0);
}

// ---------------- setup: fold/cast/repack weights (identical to R5) ----------------
__global__ void setup_k(const float* __restrict__ A, const float* __restrict__ W_sig,
                        const float* __restrict__ b_sig, const float* __restrict__ W1e,
                        const float* __restrict__ b1e, const float* __restrict__ W2e,
                        const float* __restrict__ Wc,
                        unsigned short* __restrict__ wsw1f, unsigned short* __restrict__ at_f,
                        unsigned short* __restrict__ wct_f, float* __restrict__ bw) {
  int blk = blockIdx.x, tid = threadIdx.x;
  if (blk < 512) {                       // Wsw1[l][h] = sum_h1 W_sig[l,h1]*W1e[e,h1,h]
    int e = blk >> 6, l = blk & 63, h = tid;
    const float* w1 = W1e + e * 65536 + h;
    const float* ws = W_sig + l * 256;
    float acc = 0.f;
    #pragma unroll 8
    for (int h1 = 0; h1 < 256; ++h1) acc = fmaf(ws[h1], w1[h1 * 256], acc);
    int c = h >> 7, ht = (h >> 4) & 7, col = h & 15;
    int kks = l >> 5, lgl = (l >> 3) & 3, e8 = l & 7;
    int lane = lgl * 16 + col;
    wsw1f[((((e * 2 + c) * 8 + ht) * 2 + kks) * 64 + lane) * 8 + e8] = f2bf(acc);
  } else if (blk < 576) {                // at_f: value = A[j][i]
    int idx = (blk - 512) * 256 + tid;
    int frag = idx >> 3, e8 = idx & 7;
    int it = frag >> 8, ks = (frag >> 6) & 3, lane = frag & 63;
    int j = ks * 32 + (lane >> 4) * 8 + e8, i = it * 16 + (lane & 15);
    at_f[idx] = f2bf(A[j * 128 + i]);
  } else if (blk < 608) {                // wct_f: value = Wc[l][h']
    int idx = (blk - 576) * 256 + tid;
    int frag = idx >> 3, e8 = idx & 7;
    int ht = frag >> 7, ks = (frag >> 6) & 1, lane = frag & 63;
    int l = ks * 32 + (lane >> 4) * 8 + e8, h = ht * 16 + (lane & 15);
    wct_f[idx] = f2bf(Wc[l * 128 + h]);
  } else if (blk < 624) {                // bw W2 copy
    int idx = (blk - 608) * 256 + tid;   // 0..4095
    int e = idx >> 9, r = idx & 511;
    bw[e * 768 + 256 + r] = W2e[idx];
  } else {                               // bw bias fold
    int e = blk - 624, h = tid;
    const float* w1 = W1e + e * 65536 + h;
    float acc = b1e[e * 256 + h];
    for (int h1 = 0; h1 < 256; ++h1) acc = fmaf(b_sig[h1], w1[h1 * 256], acc);
    bw[e * 768 + h] = acc;
  }
}

// ---------------- main kernel ----------------
// LDS map (35840 B -> 4 blocks/CU):
//      0: Zt [64 l][128 j] bf16 swzT(l)      (never overwritten)
//  16384: M1buf [128 i][64 l] bf16 swz8(i)   (own region)
//  32768: bw: bias1 256f | W2 512f (async gload)
__global__ __launch_bounds__(256, 4) void dec_k(
    const float* __restrict__ zs, const float* __restrict__ zcr,
    const int* __restrict__ regime, const float* __restrict__ b2e,
    const float* __restrict__ bc, const float* __restrict__ Wo,
    const float* __restrict__ bo,
    const unsigned short* __restrict__ wsw1f, const unsigned short* __restrict__ at_f,
    const unsigned short* __restrict__ wct_f, const float* __restrict__ bw,
    float* __restrict__ out) {
  __shared__ __align__(16) char sm[35840];
  float* s_bias1 = (float*)(sm + 32768);
  float* s_W2    = s_bias1 + 256;

  const int bt = ((blockIdx.x & 7) << 8) | (blockIdx.x >> 3);  // XCD swizzle
  const int tid = threadIdx.x;
  const int lane = tid & 63, wave = tid >> 6, lg = lane >> 4, l15 = lane & 15;
  int e = regime[bt >> 6]; if (e >= 8) e = 0;
  const float b2_0 = b2e[2 * e], b2_1 = b2e[2 * e + 1], bo0 = bo[0];

  const float* Z  = zs  + (size_t)bt * 8192;
  const float* Zc = zcr + (size_t)bt * 8192;

  // ---- async gload bw (bias1|W2) -> LDS ----
  if (wave < 3)
    gload16((const char*)(bw + e * 768) + tid * 16, sm + 32768 + wave * 1024);

  // ---- P0: Z fp32 -> bf16 transposed Zt ----
  float4 z0v[4], z1v[4];
  #pragma unroll
  for (int k = 0; k < 4; ++k) {
    int g = k * 256 + tid, j = (g >> 4) * 2, l0 = (g & 15) * 4;
    const float* p = Z + j * 64 + l0;
    z0v[k] = *(const float4*)p;
    z1v[k] = *(const float4*)(p + 64);
  }
  // Zc B-fragments direct from global (fp32, row-major == fragment layout)
  float4 zq[2][2][2];    // [q][ks][half]
  #pragma unroll
  for (int q = 0; q < 2; ++q) {
    int dcol = (wave * 2 + q) * 16 + l15;
    #pragma unroll
    for (int ks = 0; ks < 2; ++ks) {
      const float* p = Zc + dcol * 64 + ks * 32 + lg * 8;
      zq[q][ks][0] = *(const float4*)p;
      zq[q][ks][1] = *(const float4*)(p + 4);
    }
  }
  #pragma unroll
  for (int k = 0; k < 4; ++k) {           // Zt[l][j] transpose, swzT(l)
    int g = k * 256 + tid, j = (g >> 4) * 2, l0 = (g & 15) * 4;
    float a0[4] = {z0v[k].x, z0v[k].y, z0v[k].z, z0v[k].w};
    float a1[4] = {z1v[k].x, z1v[k].y, z1v[k].z, z1v[k].w};
    #pragma unroll
    for (int i2 = 0; i2 < 4; ++i2) {
      int l = l0 + i2;
      unsigned v = pkbf(a0[i2], a1[i2]);
      int a = (l * 256 + j * 2) ^ ((((l >> 2) ^ l) & 7) << 4);
      *(unsigned*)(sm + a) = v;
    }
  }
  __syncthreads();   // sync1: Zt + bw ready

  // convert Zc frags to bf16 in-reg
  short8 bq[2][2];
  #pragma unroll
  for (int q = 0; q < 2; ++q)
    #pragma unroll
    for (int ks = 0; ks < 2; ++ks) {
      S8 t;
      t.u[0] = pkbf(zq[q][ks][0].x, zq[q][ks][0].y);
      t.u[1] = pkbf(zq[q][ks][0].z, zq[q][ks][0].w);
      t.u[2] = pkbf(zq[q][ks][1].x, zq[q][ks][1].y);
      t.u[3] = pkbf(zq[q][ks][1].z, zq[q][ks][1].w);
      bq[q][ks] = t.s;
    }

  // ---- m1 B-fragments (At, fragment-major; R5 position) ----
  short8 abfr[2][4];
  #pragma unroll
  for (int m = 0; m < 2; ++m)
    #pragma unroll
    for (int ks = 0; ks < 4; ++ks)
      abfr[m][ks] = *(const short8*)(at_f + ((((wave * 2 + m) * 4 + ks) * 64 + lane) << 3));

  // ---- P1 mc: wave owns d-cols (wave*2+q)*16+l15, iterates all h'-tiles ----
  float cp[2] = {0.f, 0.f};
  #pragma unroll
  for (int ht = 0; ht < 8; ++ht) {
    short8 wa0 = *(const short8*)(wct_f + (((ht * 2 + 0) * 64 + lane) << 3));
    short8 wa1 = *(const short8*)(wct_f + (((ht * 2 + 1) * 64 + lane) << 3));
    float4 bcv = *(const float4*)(bc + ht * 16 + lg * 4);
    float4 wov = *(const float4*)(Wo + ht * 16 + lg * 4);
    #pragma unroll
    for (int q = 0; q < 2; ++q) {
      f32x4 acc = (f32x4){0.f, 0.f, 0.f, 0.f};
      acc = MFMA16(wa0, bq[q][0], acc);
      acc = MFMA16(wa1, bq[q][1], acc);
      #pragma unroll
      for (int r = 0; r < 4; ++r)
        cp[q] += fmaxf(acc[r] + bcv[r], 0.f) * wov[r];
    }
  }
  #pragma unroll
  for (int q = 0; q < 2; ++q) {          // reduce over lg groups -> all lanes
    cp[q] += __shfl_xor(cp[q], 16);
    cp[q] += __shfl_xor(cp[q], 32);
  }

  // ---- Wsw1 chunk0 register prefetch (R5 position: before P2) ----
  const unsigned short* wse = wsw1f + (size_t)e * 16384;
  short8 wsf0[8][2];
  #pragma unroll
  for (int ht = 0; ht < 8; ++ht)
    #pragma unroll
    for (int ks = 0; ks < 2; ++ks)
      wsf0[ht][ks] = *(const short8*)(wse + (((ht * 2 + ks) * 64 + lane) << 3));

  // ---- P2 m1: M1 = Zt(M=l) x At(N=i)  (R5 verbatim) ----
  f32x4 acc1[4][2];
  #pragma unroll
  for (int lt = 0; lt < 4; ++lt)
    #pragma unroll
    for (int m = 0; m < 2; ++m) acc1[lt][m] = (f32x4){0.f, 0.f, 0.f, 0.f};
  #pragma unroll
  for (int ks = 0; ks < 4; ++ks) {
    #pragma unroll
    for (int lt = 0; lt < 4; ++lt) {
      int arow = lt * 16 + l15;
      short8 afr = *(const short8*)(sm + ((arow * 256 + lg * 16 + ks * 64) ^
                                          ((((arow >> 2) ^ arow) & 7) << 4)));
      #pragma unroll
      for (int m = 0; m < 2; ++m) acc1[lt][m] = MFMA16(afr, abfr[m][ks], acc1[lt][m]);
    }
  }
  __syncthreads();   // sync2 (R5 schedule anchor)

  // ---- Wsw1 chunk1 register prefetch (R5 position) ----
  short8 wsf1[8][2];
  #pragma unroll
  for (int ht = 0; ht < 8; ++ht)
    #pragma unroll
    for (int ks = 0; ks < 2; ++ks)
      wsf1[ht][ks] = *(const short8*)(wse + 8192 + (((ht * 2 + ks) * 64 + lane) << 3));

  // ---- M1buf write (own region @16384; R5's exact code/bytes) ----
  #pragma unroll
  for (int lt = 0; lt < 4; ++lt) {
    int l0 = lt * 16 + lg * 4;
    #pragma unroll
    for (int m = 0; m < 2; ++m) {
      int i = (wave * 2 + m) * 16 + l15;
      unsigned lo = pkbf(acc1[lt][m][0], acc1[lt][m][1]);
      unsigned hi = pkbf(acc1[lt][m][2], acc1[lt][m][3]);
      int a = (i * 128 + l0 * 2) ^ ((i & 7) << 4);
      *(unsigned long long*)(sm + 16384 + a) = ((unsigned long long)hi << 32) | lo;
    }
  }
  short8 mbfr[2][2];
  #pragma unroll
  for (int m = 0; m < 2; ++m) {
    int brow = (wave * 2 + m) * 16 + l15;
    #pragma unroll
    for (int ks = 0; ks < 2; ++ks)
      mbfr[m][ks] = *(const short8*)(sm + 16384 +
                       ((brow * 128 + lg * 16 + ks * 64) ^ ((brow & 7) << 4)));
  }

  // ---- P3: P = Wsw1(M=h, regs) x M1buf(N=d); @W2 fused in-lane (R5 verbatim) ----
  float v0[2] = {0.f, 0.f}, v1[2] = {0.f, 0.f};
  #pragma unroll
  for (int c = 0; c < 2; ++c) {
    #pragma unroll
    for (int ht = 0; ht < 8; ++ht) {
      int h4 = c * 128 + ht * 16 + lg * 4;
      float4 b1v = *(const float4*)(s_bias1 + h4);
      float4 w2a = *(const float4*)(s_W2 + h4 * 2);
      float4 w2b = *(const float4*)(s_W2 + h4 * 2 + 4);
      #pragma unroll
      for (int m = 0; m < 2; ++m) {
        f32x4 acc = (f32x4){0.f, 0.f, 0.f, 0.f};
        if (c == 0) {
          acc = MFMA16(wsf0[ht][0], mbfr[m][0], acc);
          acc = MFMA16(wsf0[ht][1], mbfr[m][1], acc);
        } else {
          acc = MFMA16(wsf1[ht][0], mbfr[m][0], acc);
          acc = MFMA16(wsf1[ht][1], mbfr[m][1], acc);
        }
        float p0 = fmaxf(acc[0] + b1v.x, 0.f), p1 = fmaxf(acc[1] + b1v.y, 0.f);
        float p2 = fmaxf(acc[2] + b1v.z, 0.f), p3 = fmaxf(acc[3] + b1v.w, 0.f);
        v0[m] = fmaf(p0, w2a.x, fmaf(p1, w2a.z, fmaf(p2, w2b.x, fmaf(p3, w2b.z, v0[m]))));
        v1[m] = fmaf(p0, w2a.y, fmaf(p1, w2a.w, fmaf(p2, w2b.y, fmaf(p3, w2b.w, v1[m]))));
      }
    }
  }
  #pragma unroll
  for (int m = 0; m < 2; ++m) {
    v0[m] += __shfl_xor(v0[m], 16); v0[m] += __shfl_xor(v0[m], 32);
    v1[m] += __shfl_xor(v1[m], 16); v1[m] += __shfl_xor(v1[m], 32);
  }

  // ---- epilogue store from lanes 0-15 ONLY (R5's proven pattern) ----
  if (lane < 16) {
    #pragma unroll
    for (int m = 0; m < 2; ++m) {
      int d = (wave * 2 + m) * 16 + lane;
      float mu = v0[m] + b2_0 + bo0 + cp[m];
      float x = v1[m] + b2_1;
      float sg = fmaxf(x, 0.f) + log1pf(expf(-fabsf(x))) + 0.01f;
      out[(size_t)bt * 128 + d] = mu;
      out[262144 + (size_t)bt * 128 + d] = sg;
    }
  }
}

extern "C" void kernel_launch(void* const* d_in, const int* in_sizes, int n_in,
                              void* d_out, int out_size, void* d_ws, size_t ws_size,
                              hipStream_t stream) {
  const float* zs    = (const float*)d_in[0];
  const float* zcr   = (const float*)d_in[1];
  const float* A     = (const float*)d_in[2];
  const int*   reg   = (const int*)d_in[3];
  const float* W_sig = (const float*)d_in[4];
  const float* b_sig = (const float*)d_in[5];
  const float* W1e   = (const float*)d_in[6];
  const float* b1e   = (const float*)d_in[7];
  const float* W2e   = (const float*)d_in[8];
  const float* b2e   = (const float*)d_in[9];
  const float* Wc    = (const float*)d_in[10];
  const float* bcp   = (const float*)d_in[11];
  const float* Wo    = (const float*)d_in[12];
  const float* bo    = (const float*)d_in[13];

  unsigned short* wsw1f = (unsigned short*)d_ws;            // 131072 bf16 = 256 KB
  unsigned short* at_f  = wsw1f + 131072;                   // 16384 bf16 = 32 KB
  unsigned short* wct_f = at_f + 16384;                     // 8192 bf16  = 16 KB
  float* bw             = (float*)(wct_f + 8192);           // 8*768 f32  = 24 KB

  setup_k<<<632, 256, 0, stream>>>(A, W_sig, b_sig, W1e, b1e, W2e, Wc,
                                   wsw1f, at_f, wct_f, bw);
  dec_k<<<2048, 256, 0, stream>>>(zs, zcr, reg, b2e, bcp, Wo, bo,
                                  wsw1f, at_f, wct_f, bw, (float*)d_out);
}